// Round 2
// baseline (340.949 us; speedup 1.0000x reference)
//
#include <hip/hip_runtime.h>
#include <hip/hip_bf16.h>

typedef __bf16 bf16_t;
typedef __attribute__((ext_vector_type(8))) __bf16 bf16x8;
typedef __attribute__((ext_vector_type(4))) __bf16 bf16x4;
typedef __attribute__((ext_vector_type(4))) short s16x4;
typedef __attribute__((ext_vector_type(4))) float f32x4;

#define NTOK 4096
#define DIM  768
#define NH   12
#define HD   64
#define NSPLIT 2
#define KHALF (NTOK / NSPLIT)   // 2048
#define XSZ  (NTOK * DIM)       // 3,145,728
#define WQSZ (3 * DIM * DIM)    // 1,769,472
#define WPSZ (DIM * DIM)        //   589,824
// 0.125 * log2(e): folded into Q so S^T is directly in log2 domain
#define SCALE_L2E 0.18033688011112042f
// static softmax shift (shift-invariant, no overflow for |st|<~15)
#define SOFTMAX_C 12.0f

__device__ __forceinline__ bf16x8 load8(const bf16_t* p) {
    return *reinterpret_cast<const bf16x8*>(p);
}
__device__ __forceinline__ void store8(bf16_t* p, bf16x8 v) {
    *reinterpret_cast<bf16x8*>(p) = v;
}
// async global->LDS, 16B per lane; LDS dest = wave-uniform base + lane*16
__device__ __forceinline__ void gl2lds16(const bf16_t* g, bf16_t* l) {
    __builtin_amdgcn_global_load_lds(
        (const __attribute__((address_space(1))) void*)g,
        (__attribute__((address_space(3))) void*)l, 16, 0, 0);
}

// ---------------------------------------------------------------------------
// Convert fp32 inputs to bf16 once (memory-bound, ~33 MB total).
// ---------------------------------------------------------------------------
__global__ __launch_bounds__(256) void cvt_kernel(
    const float* __restrict__ x, const float* __restrict__ wq,
    const float* __restrict__ wp,
    bf16_t* __restrict__ xb, bf16_t* __restrict__ wqb, bf16_t* __restrict__ wpb)
{
    size_t i = ((size_t)blockIdx.x * 256 + threadIdx.x) * 4;
    const float* src; bf16_t* dst; size_t off;
    if (i < XSZ)             { src = x;  dst = xb;  off = i; }
    else if (i < XSZ + WQSZ) { src = wq; dst = wqb; off = i - XSZ; }
    else                     { src = wp; dst = wpb; off = i - XSZ - WQSZ; }
    float4 v = *reinterpret_cast<const float4*>(src + off);
    bf16x4 o = { (bf16_t)v.x, (bf16_t)v.y, (bf16_t)v.z, (bf16_t)v.w };
    *reinterpret_cast<bf16x4*>(dst + off) = o;
}

// ---------------------------------------------------------------------------
// QKV GEMM, m97-style: 128x128 tile, BK=32, staging via global_load_lds
// width=16 into CONTIGUOUS [128][32] LDS. 2 barriers per K-step.
// Epilogue scatter: t=0: Q[h][m][d] (*SCALE_L2E)  t=1: K[h][m][d]
//                   t=2: Vt[h][d][m] (8B stores)
// ---------------------------------------------------------------------------
__global__ __launch_bounds__(256) void qkv_gemm_kernel(
    const bf16_t* __restrict__ X, const bf16_t* __restrict__ W,
    bf16_t* __restrict__ Qo, bf16_t* __restrict__ Ko, bf16_t* __restrict__ Vt)
{
    __shared__ __align__(16) bf16_t As[128 * 32];
    __shared__ __align__(16) bf16_t Bs[128 * 32];
    const int tid  = threadIdx.x;
    const int wave = tid >> 6, lane = tid & 63;
    const int lr = lane & 15, lq = lane >> 4;
    const int M0 = blockIdx.x * 128;
    const int N0 = blockIdx.y * 128;
    const int wm = (wave >> 1) * 64, wn = (wave & 1) * 64;

    const int g_row = wave * 32 + (lane >> 2);     // + c*16
    const int g_col = (lane & 3) * 8;

    f32x4 acc[4][4] = {};

    for (int k0 = 0; k0 < DIM; k0 += 32) {
        #pragma unroll
        for (int c = 0; c < 2; ++c) {
            gl2lds16(&X[(size_t)(M0 + g_row + c * 16) * DIM + k0 + g_col],
                     &As[(wave * 32 + c * 16) * 32]);
            gl2lds16(&W[(size_t)(N0 + g_row + c * 16) * DIM + k0 + g_col],
                     &Bs[(wave * 32 + c * 16) * 32]);
        }
        __syncthreads();   // drains vmcnt: LDS tiles complete
        bf16x8 af[4], bfr[4];
        #pragma unroll
        for (int i = 0; i < 4; ++i) af[i]  = load8(&As[(wm + i * 16 + lr) * 32 + lq * 8]);
        #pragma unroll
        for (int i = 0; i < 4; ++i) bfr[i] = load8(&Bs[(wn + i * 16 + lr) * 32 + lq * 8]);
        #pragma unroll
        for (int r = 0; r < 4; ++r)
            #pragma unroll
            for (int c = 0; c < 4; ++c)
                acc[r][c] = __builtin_amdgcn_mfma_f32_16x16x32_bf16(af[r], bfr[c], acc[r][c], 0, 0, 0);
        __syncthreads();   // protect LDS before next overwrite
    }

    const int t = N0 / DIM;      // uniform per block (768 % 128 == 0)
    if (t == 2) {
        #pragma unroll
        for (int r = 0; r < 4; ++r)
            #pragma unroll
            for (int c = 0; c < 4; ++c) {
                int m0 = M0 + wm + r * 16 + lq * 4;
                int rem = N0 + wn + c * 16 + lr - 2 * DIM;
                int hh = rem >> 6, d = rem & 63;
                bf16x4 v = { (bf16_t)acc[r][c][0], (bf16_t)acc[r][c][1],
                             (bf16_t)acc[r][c][2], (bf16_t)acc[r][c][3] };
                *reinterpret_cast<bf16x4*>(&Vt[((size_t)hh * HD + d) * NTOK + m0]) = v;
            }
    } else {
        #pragma unroll
        for (int r = 0; r < 4; ++r)
            #pragma unroll
            for (int c = 0; c < 4; ++c)
                #pragma unroll
                for (int reg = 0; reg < 4; ++reg) {
                    int m = M0 + wm + r * 16 + lq * 4 + reg;
                    int rem = N0 + wn + c * 16 + lr - t * DIM;
                    int hh = rem >> 6, d = rem & 63;
                    float v = acc[r][c][reg];
                    if (t == 0) Qo[(hh * NTOK + m) * HD + d] = (bf16_t)(v * SCALE_L2E);
                    else        Ko[(hh * NTOK + m) * HD + d] = (bf16_t)v;
                }
    }
}

// ---------------------------------------------------------------------------
// Flash attention, S^T form, static-shift softmax, split-K=2, register
// prefetch of next K/V tile. XOR-swizzled stride-64 LDS:
//   element (row, d): off = row*64 + ((d/8) ^ (row&7))*8 + (d&7)
// Since every access has row&7 == lr&7 (rows differ by 16/32), the XOR is a
// per-lane constant -> zero inner-loop cost. All four LDS access patterns
// (K st/ld b128, V st b128, V ld b64) are uniform at their minimum phase
// counts and naturally aligned. LDS = 32 KiB.
// QK accumulators init to -SOFTMAX_C (sub folded into MFMA C-in).
// ---------------------------------------------------------------------------
__global__ __launch_bounds__(256, 5) void flash_attn_kernel(
    const bf16_t* __restrict__ Qb, const bf16_t* __restrict__ Kb,
    const bf16_t* __restrict__ Vtb, float* __restrict__ Opart,
    float* __restrict__ Lpart)
{
    __shared__ __align__(16) bf16_t Ks[2][64 * 64];   // [key][d]  swizzled
    __shared__ __align__(16) bf16_t Vs[2][64 * 64];   // [d][key]  swizzled
    const int tid  = threadIdx.x;
    const int wave = tid >> 6, lane = tid & 63;
    const int lr = lane & 15, lq = lane >> 4;
    const int h  = blockIdx.y;
    const int q0 = blockIdx.x * 128;
    const int sp = blockIdx.z;
    const int kt0 = sp * KHALF;
    const int NIT = KHALF / 64;     // 32

    // swizzle constants (elements)
    const int sw_st = ((tid & 7) ^ ((tid >> 3) & 7)) * 8;           // stores
    const int kc0   = (lq ^ (lr & 7)) * 8;                          // K frag d 0..31
    const int kc1   = ((4 + lq) ^ (lr & 7)) * 8;                    // K frag d 32..63
    int vc[4];
    #pragma unroll
    for (int g = 0; g < 4; ++g)
        vc[g] = ((2 * g + (lq >> 1)) ^ (lr & 7)) * 8 + (lq & 1) * 4; // V frag keys

    // Q as B-operand of S^T for two q-subtiles (rows +lr and +16+lr)
    const bf16_t* qrowA = &Qb[((size_t)h * NTOK + q0 + wave * 32 + lr) * HD];
    const bf16_t* qrowB = qrowA + 16 * HD;
    bf16x8 qa0 = load8(&qrowA[lq * 8]);
    bf16x8 qa1 = load8(&qrowA[32 + lq * 8]);
    bf16x8 qb0 = load8(&qrowB[lq * 8]);
    bf16x8 qb1 = load8(&qrowB[32 + lq * 8]);

    float la = 0.f, lb = 0.f;
    f32x4 oA[4] = {}, oB[4] = {};
    const f32x4 mc = { -SOFTMAX_C, -SOFTMAX_C, -SOFTMAX_C, -SOFTMAX_C };

    // staging: 256 threads cover 64x64 in 2 rounds of 8 elems each
    const int srA = tid >> 3;           // 0..31
    const int scA = (tid & 7) * 8;
    const bf16_t* kbase = &Kb[(size_t)h * NTOK * HD];
    const bf16_t* vbase = &Vtb[(size_t)h * HD * NTOK];

    // prefetch tile 0
    bf16x8 pk0 = load8(&kbase[(size_t)(kt0 + srA) * HD + scA]);
    bf16x8 pk1 = load8(&kbase[(size_t)(kt0 + srA + 32) * HD + scA]);
    bf16x8 pv0 = load8(&vbase[(size_t)srA * NTOK + kt0 + scA]);
    bf16x8 pv1 = load8(&vbase[(size_t)(srA + 32) * NTOK + kt0 + scA]);

    for (int it = 0; it < NIT; ++it) {
        const int kt  = kt0 + it * 64;
        const int buf = it & 1;
        store8(&Ks[buf][srA * 64 + sw_st],        pk0);
        store8(&Ks[buf][(srA + 32) * 64 + sw_st], pk1);
        store8(&Vs[buf][srA * 64 + sw_st],        pv0);
        store8(&Vs[buf][(srA + 32) * 64 + sw_st], pv1);
        __syncthreads();

        // issue next tile's global loads NOW; they complete during compute
        if (it + 1 < NIT) {
            const int kn = kt + 64;
            pk0 = load8(&kbase[(size_t)(kn + srA) * HD + scA]);
            pk1 = load8(&kbase[(size_t)(kn + srA + 32) * HD + scA]);
            pv0 = load8(&vbase[(size_t)srA * NTOK + kn + scA]);
            pv1 = load8(&vbase[(size_t)(srA + 32) * NTOK + kn + scA]);
        }

        // S^T: 4 key-subtiles; K fragments reused by both q-subtiles
        f32x4 sa[4], sb[4];
        __builtin_amdgcn_s_setprio(1);
        #pragma unroll
        for (int g = 0; g < 4; ++g) {
            bf16x8 k0 = load8(&Ks[buf][(g * 16 + lr) * 64 + kc0]);
            bf16x8 k1 = load8(&Ks[buf][(g * 16 + lr) * 64 + kc1]);
            f32x4 za = mc, zb = mc;
            za = __builtin_amdgcn_mfma_f32_16x16x32_bf16(k0, qa0, za, 0, 0, 0);
            za = __builtin_amdgcn_mfma_f32_16x16x32_bf16(k1, qa1, za, 0, 0, 0);
            zb = __builtin_amdgcn_mfma_f32_16x16x32_bf16(k0, qb0, zb, 0, 0, 0);
            zb = __builtin_amdgcn_mfma_f32_16x16x32_bf16(k1, qb1, zb, 0, 0, 0);
            sa[g] = za; sb[g] = zb;
        }
        __builtin_amdgcn_s_setprio(0);

        // static-shift softmax: p = exp2(st - C)  (C folded into acc init)
        #pragma unroll
        for (int g = 0; g < 4; ++g)
            #pragma unroll
            for (int r = 0; r < 4; ++r) {
                sa[g][r] = __builtin_amdgcn_exp2f(sa[g][r]);
                la += sa[g][r];
                sb[g][r] = __builtin_amdgcn_exp2f(sb[g][r]);
                lb += sb[g][r];
            }

        // PV: V fragments reused by both q-subtiles
        __builtin_amdgcn_s_setprio(1);
        #pragma unroll
        for (int g = 0; g < 4; ++g) {
            bf16x4 pa = { (bf16_t)sa[g][0], (bf16_t)sa[g][1],
                          (bf16_t)sa[g][2], (bf16_t)sa[g][3] };
            bf16x4 pb = { (bf16_t)sb[g][0], (bf16_t)sb[g][1],
                          (bf16_t)sb[g][2], (bf16_t)sb[g][3] };
            s16x4 psa = __builtin_bit_cast(s16x4, pa);
            s16x4 psb = __builtin_bit_cast(s16x4, pb);
            #pragma unroll
            for (int dt = 0; dt < 4; ++dt) {
                s16x4 va = *reinterpret_cast<const s16x4*>(
                    &Vs[buf][(dt * 16 + lr) * 64 + vc[g]]);
                oA[dt] = __builtin_amdgcn_mfma_f32_16x16x16bf16_1k(va, psa, oA[dt], 0, 0, 0);
                oB[dt] = __builtin_amdgcn_mfma_f32_16x16x16bf16_1k(va, psb, oB[dt], 0, 0, 0);
            }
        }
        __builtin_amdgcn_s_setprio(0);
    }

    la += __shfl_xor(la, 16); la += __shfl_xor(la, 32);
    lb += __shfl_xor(lb, 16); lb += __shfl_xor(lb, 32);
    const int ma = q0 + wave * 32 + lr;
    const int mb = ma + 16;
    if (lq == 0) {
        Lpart[((size_t)sp * NH + h) * NTOK + ma] = la;
        Lpart[((size_t)sp * NH + h) * NTOK + mb] = lb;
    }
    float* oa = &Opart[((size_t)sp * NTOK + ma) * DIM + h * HD];
    float* ob = &Opart[((size_t)sp * NTOK + mb) * DIM + h * HD];
    #pragma unroll
    for (int dt = 0; dt < 4; ++dt) {
        *reinterpret_cast<f32x4*>(&oa[dt * 16 + lq * 4]) = oA[dt];
        *reinterpret_cast<f32x4*>(&ob[dt * 16 + lq * 4]) = oB[dt];
    }
}

// ---------------------------------------------------------------------------
// Split-K combine: one pass over the NSPLIT fp32 partials, normalize by the
// summed softmax denominators, emit bf16 A for the proj GEMM. Opart is read
// exactly ONCE here (previously re-read by all 12 proj N-blocks).
// ---------------------------------------------------------------------------
__global__ __launch_bounds__(256) void combine_kernel(
    const float* __restrict__ Opart, const float* __restrict__ Lpart,
    bf16_t* __restrict__ Ab)
{
    int idx = blockIdx.x * 256 + threadIdx.x;       // over NTOK*DIM/4
    int m = idx / (DIM / 4);
    int c = (idx - m * (DIM / 4)) * 4;
    int hh = c >> 6;
    float l = 0.f;
    #pragma unroll
    for (int s = 0; s < NSPLIT; ++s)
        l += Lpart[((size_t)s * NH + hh) * NTOK + m];
    float rv = 1.f / l;
    float a0 = 0.f, a1 = 0.f, a2 = 0.f, a3 = 0.f;
    #pragma unroll
    for (int s = 0; s < NSPLIT; ++s) {
        f32x4 v = *reinterpret_cast<const f32x4*>(
            &Opart[((size_t)s * NTOK + m) * DIM + c]);
        a0 += v[0]; a1 += v[1]; a2 += v[2]; a3 += v[3];
    }
    bf16x4 o = { (bf16_t)(a0 * rv), (bf16_t)(a1 * rv),
                 (bf16_t)(a2 * rv), (bf16_t)(a3 * rv) };
    *reinterpret_cast<bf16x4*>(&Ab[(size_t)m * DIM + c]) = o;
}

// ---------------------------------------------------------------------------
// Proj GEMM: plain bf16 GEMM out = A @ Wp^T + bias, 64x64 tile, BK=32,
// gl2lds16 staging into contiguous [64][32] LDS (bank-uniform for b128
// frag reads).
// ---------------------------------------------------------------------------
__global__ __launch_bounds__(256) void proj_gemm_kernel(
    const bf16_t* __restrict__ A, const bf16_t* __restrict__ W,
    const float* __restrict__ bias, float* __restrict__ out)
{
    __shared__ __align__(16) bf16_t As[64 * 32];
    __shared__ __align__(16) bf16_t Bs[64 * 32];
    const int tid  = threadIdx.x;
    const int wave = tid >> 6, lane = tid & 63;
    const int lr = lane & 15, lq = lane >> 4;
    const int M0 = blockIdx.x * 64;
    const int N0 = blockIdx.y * 64;
    const int wr = (wave >> 1) * 32, wc = (wave & 1) * 32;
    const int g_row = tid >> 2;           // 0..63
    const int g_col = (tid & 3) * 8;

    f32x4 acc[2][2] = {};

    for (int k0 = 0; k0 < DIM; k0 += 32) {
        gl2lds16(&A[(size_t)(M0 + g_row) * DIM + k0 + g_col], &As[wave * 512]);
        gl2lds16(&W[(size_t)(N0 + g_row) * DIM + k0 + g_col], &Bs[wave * 512]);
        __syncthreads();
        bf16x8 a0 = load8(&As[(wr + lr) * 32 + lq * 8]);
        bf16x8 a1 = load8(&As[(wr + 16 + lr) * 32 + lq * 8]);
        bf16x8 b0 = load8(&Bs[(wc + lr) * 32 + lq * 8]);
        bf16x8 b1 = load8(&Bs[(wc + 16 + lr) * 32 + lq * 8]);
        acc[0][0] = __builtin_amdgcn_mfma_f32_16x16x32_bf16(a0, b0, acc[0][0], 0, 0, 0);
        acc[0][1] = __builtin_amdgcn_mfma_f32_16x16x32_bf16(a0, b1, acc[0][1], 0, 0, 0);
        acc[1][0] = __builtin_amdgcn_mfma_f32_16x16x32_bf16(a1, b0, acc[1][0], 0, 0, 0);
        acc[1][1] = __builtin_amdgcn_mfma_f32_16x16x32_bf16(a1, b1, acc[1][1], 0, 0, 0);
        __syncthreads();
    }

    #pragma unroll
    for (int r = 0; r < 2; ++r)
        #pragma unroll
        for (int c = 0; c < 2; ++c)
            #pragma unroll
            for (int reg = 0; reg < 4; ++reg) {
                int m = M0 + wr + r * 16 + lq * 4 + reg;
                int n = N0 + wc + c * 16 + lr;
                out[(size_t)m * DIM + n] = acc[r][c][reg] + bias[n];
            }
}

// ---------------------------------------------------------------------------
extern "C" void kernel_launch(void* const* d_in, const int* in_sizes, int n_in,
                              void* d_out, int out_size, void* d_ws, size_t ws_size,
                              hipStream_t stream)
{
    const float* x      = (const float*)d_in[0];
    const float* w_qkv  = (const float*)d_in[1];
    const float* w_proj = (const float*)d_in[2];
    const float* b_proj = (const float*)d_in[3];
    float* out = (float*)d_out;

    char* ws = (char*)d_ws;
    const size_t sz = (size_t)NH * NTOK * HD * sizeof(bf16_t);  // 6,291,456 B
    bf16_t* Q     = (bf16_t*)(ws);
    bf16_t* K     = (bf16_t*)(ws + sz);
    bf16_t* Vt    = (bf16_t*)(ws + 2 * sz);
    bf16_t* xb    = (bf16_t*)(ws + 3 * sz);
    bf16_t* wqb   = (bf16_t*)(ws + 3 * sz + (size_t)XSZ * 2);
    bf16_t* wpb   = (bf16_t*)(ws + 3 * sz + (size_t)(XSZ + WQSZ) * 2);
    char*   ws2   = ws + 3 * sz + (size_t)(XSZ + WQSZ + WPSZ) * 2;
    float*  Opart = (float*)ws2;                                      // NSPLIT*N*DIM fp32
    float*  Lpart = (float*)(ws2 + (size_t)NSPLIT * NTOK * DIM * 4);  // NSPLIT*NH*N fp32
    bf16_t* Ab    = xb;   // xb dead after qkv_gemm; exactly NTOK*DIM bf16

    cvt_kernel<<<dim3((XSZ + WQSZ + WPSZ) / 1024), 256, 0, stream>>>(
        x, w_qkv, w_proj, xb, wqb, wpb);
    qkv_gemm_kernel<<<dim3(NTOK / 128, (3 * DIM) / 128), 256, 0, stream>>>(
        xb, wqb, Q, K, Vt);
    flash_attn_kernel<<<dim3(NTOK / 128, NH, NSPLIT), 256, 0, stream>>>(
        Q, K, Vt, Opart, Lpart);
    combine_kernel<<<dim3((NTOK * DIM / 4) / 256), 256, 0, stream>>>(
        Opart, Lpart, Ab);
    proj_gemm_kernel<<<dim3(NTOK / 64, DIM / 64), 256, 0, stream>>>(
        Ab, wpb, b_proj, out);
}

// Round 3
// 184.708 us; speedup vs baseline: 1.8459x; 1.8459x over previous
//
#include <hip/hip_runtime.h>
#include <hip/hip_bf16.h>

typedef __bf16 bf16_t;
typedef __attribute__((ext_vector_type(8))) __bf16 bf16x8;
typedef __attribute__((ext_vector_type(4))) __bf16 bf16x4;
typedef __attribute__((ext_vector_type(4))) short s16x4;
typedef __attribute__((ext_vector_type(4))) float f32x4;

#define NTOK 4096
#define DIM  768
#define NH   12
#define HD   64
#define NSPLIT 2
#define KHALF (NTOK / NSPLIT)   // 2048
#define XSZ  (NTOK * DIM)       // 3,145,728
#define WQSZ (3 * DIM * DIM)    // 1,769,472
#define WPSZ (DIM * DIM)        //   589,824
// 0.125 * log2(e): folded into Q so S^T is directly in log2 domain
#define SCALE_L2E 0.18033688011112042f
// static softmax shift (shift-invariant, no overflow for |st|<~15)
#define SOFTMAX_C 12.0f

__device__ __forceinline__ bf16x8 load8(const bf16_t* p) {
    return *reinterpret_cast<const bf16x8*>(p);
}
__device__ __forceinline__ void store8(bf16_t* p, bf16x8 v) {
    *reinterpret_cast<bf16x8*>(p) = v;
}
// async global->LDS, 16B per lane; LDS dest = wave-uniform base + lane*16
__device__ __forceinline__ void gl2lds16(const bf16_t* g, bf16_t* l) {
    __builtin_amdgcn_global_load_lds(
        (const __attribute__((address_space(1))) void*)g,
        (__attribute__((address_space(3))) void*)l, 16, 0, 0);
}

// ---------------------------------------------------------------------------
// Convert fp32 inputs to bf16 once (memory-bound, ~33 MB total).
// ---------------------------------------------------------------------------
__global__ __launch_bounds__(256) void cvt_kernel(
    const float* __restrict__ x, const float* __restrict__ wq,
    const float* __restrict__ wp,
    bf16_t* __restrict__ xb, bf16_t* __restrict__ wqb, bf16_t* __restrict__ wpb)
{
    size_t i = ((size_t)blockIdx.x * 256 + threadIdx.x) * 4;
    const float* src; bf16_t* dst; size_t off;
    if (i < XSZ)             { src = x;  dst = xb;  off = i; }
    else if (i < XSZ + WQSZ) { src = wq; dst = wqb; off = i - XSZ; }
    else                     { src = wp; dst = wpb; off = i - XSZ - WQSZ; }
    float4 v = *reinterpret_cast<const float4*>(src + off);
    bf16x4 o = { (bf16_t)v.x, (bf16_t)v.y, (bf16_t)v.z, (bf16_t)v.w };
    *reinterpret_cast<bf16x4*>(dst + off) = o;
}

// ---------------------------------------------------------------------------
// QKV GEMM, m97-style: 128x128 tile, BK=32, staging via global_load_lds
// width=16 into CONTIGUOUS [128][32] LDS. 2 barriers per K-step.
// Epilogue scatter: t=0: Q[h][m][d] (*SCALE_L2E)  t=1: K[h][m][d]
//                   t=2: Vt[h][d][m] (8B stores)
// ---------------------------------------------------------------------------
__global__ __launch_bounds__(256) void qkv_gemm_kernel(
    const bf16_t* __restrict__ X, const bf16_t* __restrict__ W,
    bf16_t* __restrict__ Qo, bf16_t* __restrict__ Ko, bf16_t* __restrict__ Vt)
{
    __shared__ __align__(16) bf16_t As[128 * 32];
    __shared__ __align__(16) bf16_t Bs[128 * 32];
    const int tid  = threadIdx.x;
    const int wave = tid >> 6, lane = tid & 63;
    const int lr = lane & 15, lq = lane >> 4;
    const int M0 = blockIdx.x * 128;
    const int N0 = blockIdx.y * 128;
    const int wm = (wave >> 1) * 64, wn = (wave & 1) * 64;

    const int g_row = wave * 32 + (lane >> 2);     // + c*16
    const int g_col = (lane & 3) * 8;

    f32x4 acc[4][4] = {};

    for (int k0 = 0; k0 < DIM; k0 += 32) {
        #pragma unroll
        for (int c = 0; c < 2; ++c) {
            gl2lds16(&X[(size_t)(M0 + g_row + c * 16) * DIM + k0 + g_col],
                     &As[(wave * 32 + c * 16) * 32]);
            gl2lds16(&W[(size_t)(N0 + g_row + c * 16) * DIM + k0 + g_col],
                     &Bs[(wave * 32 + c * 16) * 32]);
        }
        __syncthreads();   // drains vmcnt: LDS tiles complete
        bf16x8 af[4], bfr[4];
        #pragma unroll
        for (int i = 0; i < 4; ++i) af[i]  = load8(&As[(wm + i * 16 + lr) * 32 + lq * 8]);
        #pragma unroll
        for (int i = 0; i < 4; ++i) bfr[i] = load8(&Bs[(wn + i * 16 + lr) * 32 + lq * 8]);
        #pragma unroll
        for (int r = 0; r < 4; ++r)
            #pragma unroll
            for (int c = 0; c < 4; ++c)
                acc[r][c] = __builtin_amdgcn_mfma_f32_16x16x32_bf16(af[r], bfr[c], acc[r][c], 0, 0, 0);
        __syncthreads();   // protect LDS before next overwrite
    }

    const int t = N0 / DIM;      // uniform per block (768 % 128 == 0)
    if (t == 2) {
        #pragma unroll
        for (int r = 0; r < 4; ++r)
            #pragma unroll
            for (int c = 0; c < 4; ++c) {
                int m0 = M0 + wm + r * 16 + lq * 4;
                int rem = N0 + wn + c * 16 + lr - 2 * DIM;
                int hh = rem >> 6, d = rem & 63;
                bf16x4 v = { (bf16_t)acc[r][c][0], (bf16_t)acc[r][c][1],
                             (bf16_t)acc[r][c][2], (bf16_t)acc[r][c][3] };
                *reinterpret_cast<bf16x4*>(&Vt[((size_t)hh * HD + d) * NTOK + m0]) = v;
            }
    } else {
        #pragma unroll
        for (int r = 0; r < 4; ++r)
            #pragma unroll
            for (int c = 0; c < 4; ++c)
                #pragma unroll
                for (int reg = 0; reg < 4; ++reg) {
                    int m = M0 + wm + r * 16 + lq * 4 + reg;
                    int rem = N0 + wn + c * 16 + lr - t * DIM;
                    int hh = rem >> 6, d = rem & 63;
                    float v = acc[r][c][reg];
                    if (t == 0) Qo[(hh * NTOK + m) * HD + d] = (bf16_t)(v * SCALE_L2E);
                    else        Ko[(hh * NTOK + m) * HD + d] = (bf16_t)v;
                }
    }
}

// ---------------------------------------------------------------------------
// Flash attention, S^T form, static-shift softmax, split-K=2, register
// prefetch of next K/V tile. XOR-swizzled stride-64 LDS:
//   element (row, d): off = row*64 + ((d/8) ^ (row&7))*8 + (d&7)
// Since every access has row&7 == lr&7 (rows differ by 16/32), the XOR is a
// per-lane constant -> zero inner-loop cost. All four LDS access patterns
// (K st/ld b128, V st b128, V ld b64) are uniform at their minimum phase
// counts and naturally aligned. LDS = 32 KiB.
// QK accumulators init to -SOFTMAX_C (sub folded into MFMA C-in).
// NOTE: plain __launch_bounds__(256). The (256,5) min-waves hint capped the
// allocator at ~102 regs -> arch/acc split gave 48 VGPRs -> inner-loop spill
// (432 MB scratch FETCH+WRITE, 242 us). Measured-good config is 96 VGPR.
// ---------------------------------------------------------------------------
__global__ __launch_bounds__(256) void flash_attn_kernel(
    const bf16_t* __restrict__ Qb, const bf16_t* __restrict__ Kb,
    const bf16_t* __restrict__ Vtb, float* __restrict__ Opart,
    float* __restrict__ Lpart)
{
    __shared__ __align__(16) bf16_t Ks[2][64 * 64];   // [key][d]  swizzled
    __shared__ __align__(16) bf16_t Vs[2][64 * 64];   // [d][key]  swizzled
    const int tid  = threadIdx.x;
    const int wave = tid >> 6, lane = tid & 63;
    const int lr = lane & 15, lq = lane >> 4;
    const int h  = blockIdx.y;
    const int q0 = blockIdx.x * 128;
    const int sp = blockIdx.z;
    const int kt0 = sp * KHALF;
    const int NIT = KHALF / 64;     // 32

    // swizzle constants (elements)
    const int sw_st = ((tid & 7) ^ ((tid >> 3) & 7)) * 8;           // stores
    const int kc0   = (lq ^ (lr & 7)) * 8;                          // K frag d 0..31
    const int kc1   = ((4 + lq) ^ (lr & 7)) * 8;                    // K frag d 32..63
    int vc[4];
    #pragma unroll
    for (int g = 0; g < 4; ++g)
        vc[g] = ((2 * g + (lq >> 1)) ^ (lr & 7)) * 8 + (lq & 1) * 4; // V frag keys

    // Q as B-operand of S^T for two q-subtiles (rows +lr and +16+lr)
    const bf16_t* qrowA = &Qb[((size_t)h * NTOK + q0 + wave * 32 + lr) * HD];
    const bf16_t* qrowB = qrowA + 16 * HD;
    bf16x8 qa0 = load8(&qrowA[lq * 8]);
    bf16x8 qa1 = load8(&qrowA[32 + lq * 8]);
    bf16x8 qb0 = load8(&qrowB[lq * 8]);
    bf16x8 qb1 = load8(&qrowB[32 + lq * 8]);

    float la = 0.f, lb = 0.f;
    f32x4 oA[4] = {}, oB[4] = {};
    const f32x4 mc = { -SOFTMAX_C, -SOFTMAX_C, -SOFTMAX_C, -SOFTMAX_C };

    // staging: 256 threads cover 64x64 in 2 rounds of 8 elems each
    const int srA = tid >> 3;           // 0..31
    const int scA = (tid & 7) * 8;
    const bf16_t* kbase = &Kb[(size_t)h * NTOK * HD];
    const bf16_t* vbase = &Vtb[(size_t)h * HD * NTOK];

    // prefetch tile 0
    bf16x8 pk0 = load8(&kbase[(size_t)(kt0 + srA) * HD + scA]);
    bf16x8 pk1 = load8(&kbase[(size_t)(kt0 + srA + 32) * HD + scA]);
    bf16x8 pv0 = load8(&vbase[(size_t)srA * NTOK + kt0 + scA]);
    bf16x8 pv1 = load8(&vbase[(size_t)(srA + 32) * NTOK + kt0 + scA]);

    for (int it = 0; it < NIT; ++it) {
        const int kt  = kt0 + it * 64;
        const int buf = it & 1;
        store8(&Ks[buf][srA * 64 + sw_st],        pk0);
        store8(&Ks[buf][(srA + 32) * 64 + sw_st], pk1);
        store8(&Vs[buf][srA * 64 + sw_st],        pv0);
        store8(&Vs[buf][(srA + 32) * 64 + sw_st], pv1);
        __syncthreads();

        // issue next tile's global loads NOW; they complete during compute
        if (it + 1 < NIT) {
            const int kn = kt + 64;
            pk0 = load8(&kbase[(size_t)(kn + srA) * HD + scA]);
            pk1 = load8(&kbase[(size_t)(kn + srA + 32) * HD + scA]);
            pv0 = load8(&vbase[(size_t)srA * NTOK + kn + scA]);
            pv1 = load8(&vbase[(size_t)(srA + 32) * NTOK + kn + scA]);
        }

        // S^T: 4 key-subtiles; K fragments reused by both q-subtiles
        f32x4 sa[4], sb[4];
        __builtin_amdgcn_s_setprio(1);
        #pragma unroll
        for (int g = 0; g < 4; ++g) {
            bf16x8 k0 = load8(&Ks[buf][(g * 16 + lr) * 64 + kc0]);
            bf16x8 k1 = load8(&Ks[buf][(g * 16 + lr) * 64 + kc1]);
            f32x4 za = mc, zb = mc;
            za = __builtin_amdgcn_mfma_f32_16x16x32_bf16(k0, qa0, za, 0, 0, 0);
            za = __builtin_amdgcn_mfma_f32_16x16x32_bf16(k1, qa1, za, 0, 0, 0);
            zb = __builtin_amdgcn_mfma_f32_16x16x32_bf16(k0, qb0, zb, 0, 0, 0);
            zb = __builtin_amdgcn_mfma_f32_16x16x32_bf16(k1, qb1, zb, 0, 0, 0);
            sa[g] = za; sb[g] = zb;
        }
        __builtin_amdgcn_s_setprio(0);

        // static-shift softmax: p = exp2(st - C)  (C folded into acc init)
        #pragma unroll
        for (int g = 0; g < 4; ++g)
            #pragma unroll
            for (int r = 0; r < 4; ++r) {
                sa[g][r] = __builtin_amdgcn_exp2f(sa[g][r]);
                la += sa[g][r];
                sb[g][r] = __builtin_amdgcn_exp2f(sb[g][r]);
                lb += sb[g][r];
            }

        // PV: V fragments reused by both q-subtiles
        __builtin_amdgcn_s_setprio(1);
        #pragma unroll
        for (int g = 0; g < 4; ++g) {
            bf16x4 pa = { (bf16_t)sa[g][0], (bf16_t)sa[g][1],
                          (bf16_t)sa[g][2], (bf16_t)sa[g][3] };
            bf16x4 pb = { (bf16_t)sb[g][0], (bf16_t)sb[g][1],
                          (bf16_t)sb[g][2], (bf16_t)sb[g][3] };
            s16x4 psa = __builtin_bit_cast(s16x4, pa);
            s16x4 psb = __builtin_bit_cast(s16x4, pb);
            #pragma unroll
            for (int dt = 0; dt < 4; ++dt) {
                s16x4 va = *reinterpret_cast<const s16x4*>(
                    &Vs[buf][(dt * 16 + lr) * 64 + vc[g]]);
                oA[dt] = __builtin_amdgcn_mfma_f32_16x16x16bf16_1k(va, psa, oA[dt], 0, 0, 0);
                oB[dt] = __builtin_amdgcn_mfma_f32_16x16x16bf16_1k(va, psb, oB[dt], 0, 0, 0);
            }
        }
        __builtin_amdgcn_s_setprio(0);
    }

    la += __shfl_xor(la, 16); la += __shfl_xor(la, 32);
    lb += __shfl_xor(lb, 16); lb += __shfl_xor(lb, 32);
    const int ma = q0 + wave * 32 + lr;
    const int mb = ma + 16;
    if (lq == 0) {
        Lpart[((size_t)sp * NH + h) * NTOK + ma] = la;
        Lpart[((size_t)sp * NH + h) * NTOK + mb] = lb;
    }
    float* oa = &Opart[((size_t)sp * NTOK + ma) * DIM + h * HD];
    float* ob = &Opart[((size_t)sp * NTOK + mb) * DIM + h * HD];
    #pragma unroll
    for (int dt = 0; dt < 4; ++dt) {
        *reinterpret_cast<f32x4*>(&oa[dt * 16 + lq * 4]) = oA[dt];
        *reinterpret_cast<f32x4*>(&ob[dt * 16 + lq * 4]) = oB[dt];
    }
}

// ---------------------------------------------------------------------------
// Split-K combine: one pass over the NSPLIT fp32 partials, normalize by the
// summed softmax denominators, emit bf16 A for the proj GEMM. Opart is read
// exactly ONCE here (previously re-read by all 12 proj N-blocks).
// ---------------------------------------------------------------------------
__global__ __launch_bounds__(256) void combine_kernel(
    const float* __restrict__ Opart, const float* __restrict__ Lpart,
    bf16_t* __restrict__ Ab)
{
    int idx = blockIdx.x * 256 + threadIdx.x;       // over NTOK*DIM/4
    int m = idx / (DIM / 4);
    int c = (idx - m * (DIM / 4)) * 4;
    int hh = c >> 6;
    float l = 0.f;
    #pragma unroll
    for (int s = 0; s < NSPLIT; ++s)
        l += Lpart[((size_t)s * NH + hh) * NTOK + m];
    float rv = 1.f / l;
    float a0 = 0.f, a1 = 0.f, a2 = 0.f, a3 = 0.f;
    #pragma unroll
    for (int s = 0; s < NSPLIT; ++s) {
        f32x4 v = *reinterpret_cast<const f32x4*>(
            &Opart[((size_t)s * NTOK + m) * DIM + c]);
        a0 += v[0]; a1 += v[1]; a2 += v[2]; a3 += v[3];
    }
    bf16x4 o = { (bf16_t)(a0 * rv), (bf16_t)(a1 * rv),
                 (bf16_t)(a2 * rv), (bf16_t)(a3 * rv) };
    *reinterpret_cast<bf16x4*>(&Ab[(size_t)m * DIM + c]) = o;
}

// ---------------------------------------------------------------------------
// Proj GEMM: plain bf16 GEMM out = A @ Wp^T + bias, 64x64 tile, BK=32,
// gl2lds16 staging into contiguous [64][32] LDS (bank-uniform for b128
// frag reads).
// ---------------------------------------------------------------------------
__global__ __launch_bounds__(256) void proj_gemm_kernel(
    const bf16_t* __restrict__ A, const bf16_t* __restrict__ W,
    const float* __restrict__ bias, float* __restrict__ out)
{
    __shared__ __align__(16) bf16_t As[64 * 32];
    __shared__ __align__(16) bf16_t Bs[64 * 32];
    const int tid  = threadIdx.x;
    const int wave = tid >> 6, lane = tid & 63;
    const int lr = lane & 15, lq = lane >> 4;
    const int M0 = blockIdx.x * 64;
    const int N0 = blockIdx.y * 64;
    const int wr = (wave >> 1) * 32, wc = (wave & 1) * 32;
    const int g_row = tid >> 2;           // 0..63
    const int g_col = (tid & 3) * 8;

    f32x4 acc[2][2] = {};

    for (int k0 = 0; k0 < DIM; k0 += 32) {
        gl2lds16(&A[(size_t)(M0 + g_row) * DIM + k0 + g_col], &As[wave * 512]);
        gl2lds16(&W[(size_t)(N0 + g_row) * DIM + k0 + g_col], &Bs[wave * 512]);
        __syncthreads();
        bf16x8 a0 = load8(&As[(wr + lr) * 32 + lq * 8]);
        bf16x8 a1 = load8(&As[(wr + 16 + lr) * 32 + lq * 8]);
        bf16x8 b0 = load8(&Bs[(wc + lr) * 32 + lq * 8]);
        bf16x8 b1 = load8(&Bs[(wc + 16 + lr) * 32 + lq * 8]);
        acc[0][0] = __builtin_amdgcn_mfma_f32_16x16x32_bf16(a0, b0, acc[0][0], 0, 0, 0);
        acc[0][1] = __builtin_amdgcn_mfma_f32_16x16x32_bf16(a0, b1, acc[0][1], 0, 0, 0);
        acc[1][0] = __builtin_amdgcn_mfma_f32_16x16x32_bf16(a1, b0, acc[1][0], 0, 0, 0);
        acc[1][1] = __builtin_amdgcn_mfma_f32_16x16x32_bf16(a1, b1, acc[1][1], 0, 0, 0);
        __syncthreads();
    }

    #pragma unroll
    for (int r = 0; r < 2; ++r)
        #pragma unroll
        for (int c = 0; c < 2; ++c)
            #pragma unroll
            for (int reg = 0; reg < 4; ++reg) {
                int m = M0 + wr + r * 16 + lq * 4 + reg;
                int n = N0 + wc + c * 16 + lr;
                out[(size_t)m * DIM + n] = acc[r][c][reg] + bias[n];
            }
}

// ---------------------------------------------------------------------------
extern "C" void kernel_launch(void* const* d_in, const int* in_sizes, int n_in,
                              void* d_out, int out_size, void* d_ws, size_t ws_size,
                              hipStream_t stream)
{
    const float* x      = (const float*)d_in[0];
    const float* w_qkv  = (const float*)d_in[1];
    const float* w_proj = (const float*)d_in[2];
    const float* b_proj = (const float*)d_in[3];
    float* out = (float*)d_out;

    char* ws = (char*)d_ws;
    const size_t sz = (size_t)NH * NTOK * HD * sizeof(bf16_t);  // 6,291,456 B
    bf16_t* Q     = (bf16_t*)(ws);
    bf16_t* K     = (bf16_t*)(ws + sz);
    bf16_t* Vt    = (bf16_t*)(ws + 2 * sz);
    bf16_t* xb    = (bf16_t*)(ws + 3 * sz);
    bf16_t* wqb   = (bf16_t*)(ws + 3 * sz + (size_t)XSZ * 2);
    bf16_t* wpb   = (bf16_t*)(ws + 3 * sz + (size_t)(XSZ + WQSZ) * 2);
    char*   ws2   = ws + 3 * sz + (size_t)(XSZ + WQSZ + WPSZ) * 2;
    float*  Opart = (float*)ws2;                                      // NSPLIT*N*DIM fp32
    float*  Lpart = (float*)(ws2 + (size_t)NSPLIT * NTOK * DIM * 4);  // NSPLIT*NH*N fp32
    bf16_t* Ab    = xb;   // xb dead after qkv_gemm; exactly NTOK*DIM bf16

    cvt_kernel<<<dim3((XSZ + WQSZ + WPSZ) / 1024), 256, 0, stream>>>(
        x, w_qkv, w_proj, xb, wqb, wpb);
    qkv_gemm_kernel<<<dim3(NTOK / 128, (3 * DIM) / 128), 256, 0, stream>>>(
        xb, wqb, Q, K, Vt);
    flash_attn_kernel<<<dim3(NTOK / 128, NH, NSPLIT), 256, 0, stream>>>(
        Q, K, Vt, Opart, Lpart);
    combine_kernel<<<dim3((NTOK * DIM / 4) / 256), 256, 0, stream>>>(
        Opart, Lpart, Ab);
    proj_gemm_kernel<<<dim3(NTOK / 64, DIM / 64), 256, 0, stream>>>(
        Ab, wpb, b_proj, out);
}